// Round 1
// baseline (310.740 us; speedup 1.0000x reference)
//
#include <hip/hip_runtime.h>
#include <stdint.h>

// Problem constants (SelfAttention: B=4, T=2048, EMB=1024, causal + key padding)
#define TB 2048
#define DD 1024
#define NWAVE 8

typedef __bf16 bf16x8 __attribute__((ext_vector_type(8)));
typedef float  f32x16 __attribute__((ext_vector_type(16)));
typedef int    int4v  __attribute__((ext_vector_type(4)));

// truncate-to-bf16 pack: result = (bf16(hi)<<16) | bf16(lo)
__device__ __forceinline__ unsigned pack2(float hi, float lo) {
  return (__float_as_uint(hi) & 0xffff0000u) | (__float_as_uint(lo) >> 16);
}

__device__ __forceinline__ bf16x8 pack8(const float f[8]) {
  int4v w;
  w.x = (int)pack2(f[1], f[0]);
  w.y = (int)pack2(f[3], f[2]);
  w.z = (int)pack2(f[5], f[4]);
  w.w = (int)pack2(f[7], f[6]);
  return __builtin_bit_cast(bf16x8, w);
}

// Flash-attention fwd, fp32 in/out, bf16 MFMA internally.
// Grid: 256 blocks (one per (batch, 32-q-row tile)), 512 threads (8 waves).
// Wave w owns d-slice [128w, 128w+128).
__global__ __launch_bounds__(512, 2)
void fa_fwd_f32_v1(const float* __restrict__ Q, const float* __restrict__ K,
                   const float* __restrict__ V, const int* __restrict__ AM,
                   float* __restrict__ O)
{
  // 8 waves x 32 planes x 68 floats (stride-68 keeps ds_read_b128 spread over banks)
  __shared__ __align__(16) float lds_part[NWAVE][32 * 68];      // 69632 B
  __shared__ __align__(16) unsigned short lds_P[32][72];        // P tile, bf16, padded
  __shared__ float lds_m[32], lds_l[32], lds_scale[32];
  __shared__ unsigned lds_mask32[TB / 4];                       // 4 mask bytes per word
  __shared__ int lds_tv[32];                                    // per-K-tile any-valid

  const int tid  = threadIdx.x;
  const int w    = tid >> 6;
  const int lane = tid & 63;
  const int lo5  = lane & 31;
  const int hi   = lane >> 5;

  // XCD-chunked, causal-balanced (b, qtile) mapping.
  // blockIdx % 8 = XCD (hw round-robin). XCD 2b+0 -> qtiles {0..15,48..63},
  // XCD 2b+1 -> {16..47}: equal total causal work, same-batch K/V locality.
  const int bid  = blockIdx.x;
  const int xcd  = bid & 7;
  const int slot = bid >> 3;        // 0..31
  const int b    = xcd >> 1;
  const int half = xcd & 1;
  const int qt   = half ? (16 + slot) : (slot < 16 ? slot : 32 + slot);
  const int q0   = qt << 5;

  // ---- stage padding mask + per-tile validity ----
  const int* mrow = AM + b * TB;
  const int4v mi = *(const int4v*)(mrow + 4 * tid);
  const unsigned mw = (mi.x ? 1u : 0u) | (mi.y ? 0x100u : 0u) |
                      (mi.z ? 0x10000u : 0u) | (mi.w ? 0x1000000u : 0u);
  lds_mask32[tid] = mw;
  if (tid < 32) { lds_tv[tid] = 0; lds_m[tid] = -1e30f; lds_l[tid] = 0.0f; }
  __syncthreads();
  if (mw) lds_tv[tid >> 4] = 1;     // 16 threads cover one 64-key tile

  // ---- load Q fragments (scaled by 1/sqrt(1024) = 1/32, exact in bf16) ----
  // A-frag (32x16): lane holds A[lo5][8*hi + j], j=0..7
  bf16x8 qf[8];
  {
    const float* qrow = Q + ((size_t)b * TB + q0 + lo5) * DD + w * 128 + hi * 8;
    #pragma unroll
    for (int kk = 0; kk < 8; ++kk) {
      const float4 a = *(const float4*)(qrow + kk * 16);
      const float4 c = *(const float4*)(qrow + kk * 16 + 4);
      const float f[8] = {a.x * 0.03125f, a.y * 0.03125f, a.z * 0.03125f, a.w * 0.03125f,
                          c.x * 0.03125f, c.y * 0.03125f, c.z * 0.03125f, c.w * 0.03125f};
      qf[kk] = pack8(f);
    }
  }

  f32x16 oacc[4] = {f32x16{}, f32x16{}, f32x16{}, f32x16{}};

  const float* kbat = K + (size_t)b * TB * DD + w * 128 + hi * 8;
  const float* vbat = V + (size_t)b * TB * DD + w * 128;

  __syncthreads();

  const int nkt = (qt >> 1) + 1;    // causal: keys <= q0+31
  for (int kt = 0; kt < nkt; ++kt) {
    if (!lds_tv[kt]) continue;      // fully-padded tile (uniform branch)
    const int k0 = kt << 6;

    // ---- QK^T partial over this wave's 128-d slice (2 key-blocks of 32) ----
    f32x16 s0{}, s1{};
    const float* kb0 = kbat + (size_t)(k0 + lo5) * DD;
    #pragma unroll
    for (int kk = 0; kk < 8; ++kk) {
      const float4 a0 = *(const float4*)(kb0 + kk * 16);
      const float4 a1 = *(const float4*)(kb0 + kk * 16 + 4);
      const float f0[8] = {a0.x, a0.y, a0.z, a0.w, a1.x, a1.y, a1.z, a1.w};
      s0 = __builtin_amdgcn_mfma_f32_32x32x16_bf16(qf[kk], pack8(f0), s0, 0, 0, 0);
      const float4 b0 = *(const float4*)(kb0 + (size_t)32 * DD + kk * 16);
      const float4 b1 = *(const float4*)(kb0 + (size_t)32 * DD + kk * 16 + 4);
      const float f1[8] = {b0.x, b0.y, b0.z, b0.w, b1.x, b1.y, b1.z, b1.w};
      s1 = __builtin_amdgcn_mfma_f32_32x32x16_bf16(qf[kk], pack8(f1), s1, 0, 0, 0);
    }
    {
      float* wp = lds_part[w];
      const int pos = lo5 + (hi << 5);
      #pragma unroll
      for (int r = 0; r < 16; ++r) {
        wp[r * 68 + pos]        = s0[r];
        wp[(16 + r) * 68 + pos] = s1[r];
      }
    }
    __syncthreads();  // partials visible

    // ---- cross-wave reduce + masks + online softmax ----
    // thread t: row r = t>>4 (q0+r), keys 4g..4g+3 (g = t&15); same-row lanes
    // are 16 contiguous lanes of one wave -> shfl reduce is safe.
    {
      const int r = tid >> 4, g = tid & 15;
      const int regp  = (r & 3) | (((r >> 3) & 3) << 2);
      const int plane = ((g >> 3) << 4) + regp;          // kb*16 + reg
      const int pos   = ((4 * g) & 31) + (((r >> 2) & 1) << 5);
      float s[4] = {0.f, 0.f, 0.f, 0.f};
      #pragma unroll
      for (int ww = 0; ww < 8; ++ww) {
        const float4 v4 = *(const float4*)&lds_part[ww][plane * 68 + pos];
        s[0] += v4.x; s[1] += v4.y; s[2] += v4.z; s[3] += v4.w;
      }
      const unsigned mv = lds_mask32[(k0 >> 2) + g];
      const int q = q0 + r;
      #pragma unroll
      for (int i = 0; i < 4; ++i) {
        const int kg = k0 + 4 * g + i;
        const bool ok = (((mv >> (8 * i)) & 0xffu) != 0u) && (kg <= q);
        if (!ok) s[i] = -1e30f;
      }
      float mx = fmaxf(fmaxf(s[0], s[1]), fmaxf(s[2], s[3]));
      #pragma unroll
      for (int d = 1; d < 16; d <<= 1) mx = fmaxf(mx, __shfl_xor(mx, d, 64));
      const float mold = lds_m[r];              // wave-synchronous read-before-write
      const float mnew = fmaxf(mold, mx);
      float p[4], ls = 0.f;
      #pragma unroll
      for (int i = 0; i < 4; ++i) { p[i] = __expf(s[i] - mnew); ls += p[i]; }
      #pragma unroll
      for (int d = 1; d < 16; d <<= 1) ls += __shfl_xor(ls, d, 64);
      const float resc = __expf(mold - mnew);
      if (g == 0) {
        lds_m[r]     = mnew;
        lds_l[r]     = lds_l[r] * resc + ls;
        lds_scale[r] = resc;
      }
      unsigned* pp = (unsigned*)&lds_P[r][4 * g];
      pp[0] = pack2(p[1], p[0]);
      pp[1] = pack2(p[3], p[2]);
    }
    __syncthreads();  // P + scale visible

    // ---- rescale O, then P x V into O ----
    {
      float sc[16];
      #pragma unroll
      for (int reg = 0; reg < 16; ++reg)
        sc[reg] = lds_scale[(reg & 3) + ((reg >> 2) << 3) + (hi << 2)];
      #pragma unroll
      for (int nb = 0; nb < 4; ++nb) {
        #pragma unroll
        for (int reg = 0; reg < 16; ++reg) oacc[nb][reg] *= sc[reg];
      }
      bf16x8 pf[4];
      #pragma unroll
      for (int kc = 0; kc < 4; ++kc)
        pf[kc] = __builtin_bit_cast(bf16x8, *(const int4v*)&lds_P[lo5][kc * 16 + hi * 8]);

      const float* vb = vbat + (size_t)k0 * DD + lo5;
      #pragma unroll
      for (int kc = 0; kc < 4; ++kc) {
        const float* vr = vb + (size_t)(kc * 16 + hi * 8) * DD;
        float fv[4][8];
        #pragma unroll
        for (int j = 0; j < 8; ++j) {
          const float* vrj = vr + (size_t)j * DD;
          #pragma unroll
          for (int nb = 0; nb < 4; ++nb) fv[nb][j] = vrj[nb * 32];
        }
        #pragma unroll
        for (int nb = 0; nb < 4; ++nb)
          oacc[nb] = __builtin_amdgcn_mfma_f32_32x32x16_bf16(pf[kc], pack8(fv[nb]), oacc[nb], 0, 0, 0);
      }
    }
  }

  // ---- epilogue: divide by l, store ----
  float il[16];
  #pragma unroll
  for (int reg = 0; reg < 16; ++reg)
    il[reg] = 1.0f / lds_l[(reg & 3) + ((reg >> 2) << 3) + (hi << 2)];
  float* ob = O + ((size_t)b * TB + q0) * DD + w * 128;
  #pragma unroll
  for (int nb = 0; nb < 4; ++nb) {
    #pragma unroll
    for (int reg = 0; reg < 16; ++reg) {
      const int row = (reg & 3) + ((reg >> 2) << 3) + (hi << 2);
      ob[(size_t)row * DD + nb * 32 + lo5] = oacc[nb][reg] * il[reg];
    }
  }
}

extern "C" void kernel_launch(void* const* d_in, const int* in_sizes, int n_in,
                              void* d_out, int out_size, void* d_ws, size_t ws_size,
                              hipStream_t stream) {
  const float* Q  = (const float*)d_in[0];
  const float* K  = (const float*)d_in[1];
  const float* V  = (const float*)d_in[2];
  const int*   AM = (const int*)d_in[3];
  float* O = (float*)d_out;
  (void)in_sizes; (void)n_in; (void)out_size; (void)d_ws; (void)ws_size;
  hipLaunchKernelGGL(fa_fwd_f32_v1, dim3(256), dim3(512), 0, stream, Q, K, V, AM, O);
}

// Round 2
// 149.809 us; speedup vs baseline: 2.0742x; 2.0742x over previous
//
#include <hip/hip_runtime.h>
#include <stdint.h>

// SelfAttention: B=4, T=2048, EMB=1024, causal + key padding (last 256 keys)
#define TB 2048
#define DD 1024

typedef __bf16 bf16x8 __attribute__((ext_vector_type(8)));
typedef float  f32x16 __attribute__((ext_vector_type(16)));
typedef int    int4v  __attribute__((ext_vector_type(4)));

__device__ __forceinline__ unsigned pack2(float hi, float lo) {
  return (__float_as_uint(hi) & 0xffff0000u) | (__float_as_uint(lo) >> 16);
}
__device__ __forceinline__ bf16x8 pack8(const float f[8]) {
  int4v w;
  w.x = (int)pack2(f[1], f[0]);
  w.y = (int)pack2(f[3], f[2]);
  w.z = (int)pack2(f[5], f[4]);
  w.w = (int)pack2(f[7], f[6]);
  return __builtin_bit_cast(bf16x8, w);
}

// ============================ pre-pass kernels ============================
// Kf layout: [b][kt=T/32][ds=D/16][lane=64][8]  (bf16)
//   element (b, 32*kt + (lane&31), 16*ds + 8*(lane>>5) + j)
__global__ __launch_bounds__(256)
void conv_k_bf16(const float* __restrict__ K, unsigned short* __restrict__ Kf) {
  const int b  = blockIdx.x >> 6;
  const int kt = blockIdx.x & 63;
  const int lt  = threadIdx.x & 63;
  const int row = lt & 31, hi = lt >> 5;
  const int wv  = threadIdx.x >> 6;            // 0..3
  const float* src = K + ((size_t)(b * TB + kt * 32 + row)) * DD + hi * 8;
  unsigned short* dst = Kf + ((size_t)(b * 64 + kt) * 64) * 512 + lt * 8;
  #pragma unroll
  for (int i = 0; i < 16; ++i) {
    const int ds = wv + 4 * i;
    const float4 a = *(const float4*)(src + ds * 16);
    const float4 c = *(const float4*)(src + ds * 16 + 4);
    const float f[8] = {a.x, a.y, a.z, a.w, c.x, c.y, c.z, c.w};
    *(int4v*)(dst + (size_t)ds * 512) = __builtin_bit_cast(int4v, pack8(f));
  }
}

// Vf layout: [b][dt=D/32][ks=T/16][lane=64][8]  (bf16, transposed)
//   element = V[b][16*ks + 8*(lane>>5) + j][32*dt + (lane&31)]
__global__ __launch_bounds__(256)
void conv_v_bf16t(const float* __restrict__ V, unsigned short* __restrict__ Vf) {
  __shared__ __align__(16) float t[64 * 260];          // 64 keys x 256 d, pad
  const int bid = blockIdx.x;
  const int b   = bid >> 7;            // 4
  const int kb  = (bid >> 2) & 31;     // T/64 = 32
  const int db  = bid & 3;             // D/256 = 4
  const int k0 = kb * 64, d0 = db * 256;
  // stage 64x256 fp32 tile, coalesced
  {
    const int f = threadIdx.x & 63;          // float4 col
    const int r0 = threadIdx.x >> 6;         // 0..3
    #pragma unroll
    for (int i = 0; i < 16; ++i) {
      const int kloc = r0 + 4 * i;
      const float4 v4 = *(const float4*)(V + ((size_t)(b * TB + k0 + kloc)) * DD + d0 + f * 4);
      *(float4*)(t + kloc * 260 + f * 4) = v4;
    }
  }
  __syncthreads();
  const int lt  = threadIdx.x & 63;
  const int lo5 = lt & 31, hi = lt >> 5;
  const int kk  = threadIdx.x >> 6;          // 0..3 (16-key step)
  #pragma unroll
  for (int dd = 0; dd < 8; ++dd) {           // 32-d block within 256
    float f[8];
    #pragma unroll
    for (int j = 0; j < 8; ++j)
      f[j] = t[(kk * 16 + hi * 8 + j) * 260 + dd * 32 + lo5];
    unsigned short* dst = Vf +
        (((size_t)(b * 32 + (d0 >> 5) + dd) * 128 + (k0 >> 4) + kk) * 64 + lt) * 8;
    *(int4v*)dst = __builtin_bit_cast(int4v, pack8(f));
  }
}

// ============================ main kernel (v2) ============================
// 256 blocks (b, 32-q-row tile), 512 threads = 8 waves.
// Per 256-key tile: wave w computes full-d S[32x32] for keys [k0+32w, +32);
// softmax through LDS; PV: wave w owns d-slice [128w, +128).
__global__ __launch_bounds__(512, 2)
void fa_fwd_f32_v2(const float* __restrict__ Q, const int* __restrict__ AM,
                   const unsigned short* __restrict__ Kf,
                   const unsigned short* __restrict__ Vf,
                   float* __restrict__ O)
{
  __shared__ __align__(16) unsigned short lds_Q[64 * 64 * 8];   // 65536 B, frag order
  __shared__ __align__(16) float lds_S[32 * 260];               // 33280 B
  __shared__ __align__(16) unsigned short lds_P[32 * 256];      // 16384 B (XOR swizzled)
  __shared__ float lds_m[32], lds_l[32], lds_scale[32];
  __shared__ unsigned lds_mask32[TB / 4];
  __shared__ int lds_tv[8];                                     // per-256-key-tile validity

  const int tid  = threadIdx.x;
  const int w    = tid >> 6;
  const int lane = tid & 63;
  const int lo5  = lane & 31;
  const int hi   = lane >> 5;

  // XCD-chunked causal-balanced mapping (same as v1)
  const int bid  = blockIdx.x;
  const int xcd  = bid & 7;
  const int slot = bid >> 3;
  const int b    = xcd >> 1;
  const int half = xcd & 1;
  const int qt   = half ? (16 + slot) : (slot < 16 ? slot : 32 + slot);
  const int q0   = qt << 5;

  // ---- stage padding mask + init ----
  const int4v mi = *(const int4v*)(AM + b * TB + 4 * tid);
  const unsigned mw = (mi.x ? 1u : 0u) | (mi.y ? 0x100u : 0u) |
                      (mi.z ? 0x10000u : 0u) | (mi.w ? 0x1000000u : 0u);
  lds_mask32[tid] = mw;
  if (tid < 8)  lds_tv[tid] = 0;
  if (tid < 32) { lds_m[tid] = -1e30f; lds_l[tid] = 0.0f; }
  __syncthreads();
  if (mw) lds_tv[tid >> 6] = 1;

  // ---- stage Q tile (scaled 1/32, bf16, fragment order) ----
  {
    const int row = lane & 31, qhi = lane >> 5;
    const float* qsrc = Q + ((size_t)(b * TB + q0 + row)) * DD + qhi * 8;
    #pragma unroll
    for (int i = 0; i < 8; ++i) {
      const int ds = w + 8 * i;
      const float4 a = *(const float4*)(qsrc + ds * 16);
      const float4 c = *(const float4*)(qsrc + ds * 16 + 4);
      const float f[8] = {a.x * 0.03125f, a.y * 0.03125f, a.z * 0.03125f, a.w * 0.03125f,
                          c.x * 0.03125f, c.y * 0.03125f, c.z * 0.03125f, c.w * 0.03125f};
      *(int4v*)(lds_Q + (((size_t)ds << 6 | lane) << 3)) = __builtin_bit_cast(int4v, pack8(f));
    }
  }

  f32x16 oacc[4] = {f32x16{}, f32x16{}, f32x16{}, f32x16{}};

  const char* kf_wave = (const char*)Kf + ((size_t)b * 64 + w) * 65536 + lane * 16;
  const char* vf_b    = (const char*)Vf + (size_t)b * 4194304 + (size_t)(w * 4) * 131072 + lane * 16;
  const char* pbytes  = (const char*)lds_P;

  __syncthreads();

  const int nkt = (qt >> 3) + 1;      // 256-key tiles, causal bound
  for (int kt = 0; kt < nkt; ++kt) {
    if (!lds_tv[kt]) continue;
    const int k0 = kt << 8;

    // ---- QK^T: wave w, keys k0+32w..+31, full d (64 MFMA) ----
    f32x16 s0{}, s1{};
    {
      const char* kp = kf_wave + (size_t)kt * 524288;   // 8 kt-blocks * 65536
      #pragma unroll 4
      for (int ds = 0; ds < 64; ds += 2) {
        const bf16x8 a0 = *(const bf16x8*)((const char*)lds_Q + ((ds << 6 | lane) << 4));
        const bf16x8 b0 = *(const bf16x8*)kp;
        const bf16x8 a1 = *(const bf16x8*)((const char*)lds_Q + (((ds + 1) << 6 | lane) << 4));
        const bf16x8 b1 = *(const bf16x8*)(kp + 1024);
        s0 = __builtin_amdgcn_mfma_f32_32x32x16_bf16(a0, b0, s0, 0, 0, 0);
        s1 = __builtin_amdgcn_mfma_f32_32x32x16_bf16(a1, b1, s1, 0, 0, 0);
        kp += 2048;
      }
    }
    // write S[row][32w + lo5]
    #pragma unroll
    for (int reg = 0; reg < 16; ++reg) {
      const int row = (reg & 3) + ((reg >> 2) << 3) + (hi << 2);
      lds_S[row * 260 + (w << 5) + lo5] = s0[reg] + s1[reg];
    }
    __syncthreads();

    // ---- softmax: thread (r = tid>>4, g = tid&15) covers keys 16g..16g+15 ----
    {
      const int r = tid >> 4, g = tid & 15;
      float s[16];
      *(float4*)(s + 0)  = *(const float4*)(lds_S + r * 260 + g * 16 + 0);
      *(float4*)(s + 4)  = *(const float4*)(lds_S + r * 260 + g * 16 + 4);
      *(float4*)(s + 8)  = *(const float4*)(lds_S + r * 260 + g * 16 + 8);
      *(float4*)(s + 12) = *(const float4*)(lds_S + r * 260 + g * 16 + 12);
      const int q = q0 + r;
      #pragma unroll
      for (int i = 0; i < 16; ++i) {
        const unsigned mword = lds_mask32[(k0 >> 2) + 4 * g + (i >> 2)];
        const bool ok = (((mword >> (8 * (i & 3))) & 0xffu) != 0u) && (k0 + 16 * g + i <= q);
        if (!ok) s[i] = -1e30f;
      }
      float mx = s[0];
      #pragma unroll
      for (int i = 1; i < 16; ++i) mx = fmaxf(mx, s[i]);
      #pragma unroll
      for (int d = 1; d < 16; d <<= 1) mx = fmaxf(mx, __shfl_xor(mx, d, 64));
      const float mold = lds_m[r];
      const float mnew = fmaxf(mold, mx);
      float p[16], ls = 0.f;
      #pragma unroll
      for (int i = 0; i < 16; ++i) { p[i] = __expf(s[i] - mnew); ls += p[i]; }
      #pragma unroll
      for (int d = 1; d < 16; d <<= 1) ls += __shfl_xor(ls, d, 64);
      if (g == 0) {
        const float resc = __expf(mold - mnew);
        lds_m[r]     = mnew;
        lds_l[r]     = lds_l[r] * resc + ls;
        lds_scale[r] = resc;
      }
      int4v w0, w1;
      w0.x = (int)pack2(p[1],  p[0]);  w0.y = (int)pack2(p[3],  p[2]);
      w0.z = (int)pack2(p[5],  p[4]);  w0.w = (int)pack2(p[7],  p[6]);
      w1.x = (int)pack2(p[9],  p[8]);  w1.y = (int)pack2(p[11], p[10]);
      w1.z = (int)pack2(p[13], p[12]); w1.w = (int)pack2(p[15], p[14]);
      char* pb = (char*)lds_P;
      *(int4v*)(pb + ((r * 512 + g * 32 + 0)  ^ ((r & 15) << 4))) = w0;
      *(int4v*)(pb + ((r * 512 + g * 32 + 16) ^ ((r & 15) << 4))) = w1;
    }
    __syncthreads();

    // ---- rescale O, then P x V ----
    {
      float sc[16];
      #pragma unroll
      for (int reg = 0; reg < 16; ++reg)
        sc[reg] = lds_scale[(reg & 3) + ((reg >> 2) << 3) + (hi << 2)];
      #pragma unroll
      for (int nb = 0; nb < 4; ++nb)
        #pragma unroll
        for (int reg = 0; reg < 16; ++reg) oacc[nb][reg] *= sc[reg];

      const char* vp0 = vf_b + (size_t)kt * 16384;     // 16 ks-steps * 1024B
      #pragma unroll 4
      for (int kc = 0; kc < 16; ++kc) {
        const bf16x8 pa = *(const bf16x8*)(pbytes +
            ((lo5 * 512 + kc * 32 + hi * 16) ^ ((lo5 & 15) << 4)));
        const char* vp = vp0 + kc * 1024;
        #pragma unroll
        for (int nb = 0; nb < 4; ++nb)
          oacc[nb] = __builtin_amdgcn_mfma_f32_32x32x16_bf16(
              pa, *(const bf16x8*)(vp + (size_t)nb * 131072), oacc[nb], 0, 0, 0);
      }
    }
    __syncthreads();   // protect lds_S/lds_P reuse next iteration
  }

  // ---- epilogue ----
  float il[16];
  #pragma unroll
  for (int reg = 0; reg < 16; ++reg)
    il[reg] = 1.0f / lds_l[(reg & 3) + ((reg >> 2) << 3) + (hi << 2)];
  float* ob = O + ((size_t)b * TB + q0) * DD + w * 128;
  #pragma unroll
  for (int nb = 0; nb < 4; ++nb) {
    #pragma unroll
    for (int reg = 0; reg < 16; ++reg) {
      const int row = (reg & 3) + ((reg >> 2) << 3) + (hi << 2);
      ob[(size_t)row * DD + nb * 32 + lo5] = oacc[nb][reg] * il[reg];
    }
  }
}

// ============================ fallback (v1, known good) ============================
__global__ __launch_bounds__(512, 2)
void fa_fwd_f32_v1(const float* __restrict__ Q, const float* __restrict__ K,
                   const float* __restrict__ V, const int* __restrict__ AM,
                   float* __restrict__ O)
{
  __shared__ __align__(16) float lds_part[8][32 * 68];
  __shared__ __align__(16) unsigned short lds_P[32][72];
  __shared__ float lds_m[32], lds_l[32], lds_scale[32];
  __shared__ unsigned lds_mask32[TB / 4];
  __shared__ int lds_tv[32];

  const int tid  = threadIdx.x;
  const int w    = tid >> 6;
  const int lane = tid & 63;
  const int lo5  = lane & 31;
  const int hi   = lane >> 5;

  const int bid  = blockIdx.x;
  const int xcd  = bid & 7;
  const int slot = bid >> 3;
  const int b    = xcd >> 1;
  const int half = xcd & 1;
  const int qt   = half ? (16 + slot) : (slot < 16 ? slot : 32 + slot);
  const int q0   = qt << 5;

  const int* mrow = AM + b * TB;
  const int4v mi = *(const int4v*)(mrow + 4 * tid);
  const unsigned mw = (mi.x ? 1u : 0u) | (mi.y ? 0x100u : 0u) |
                      (mi.z ? 0x10000u : 0u) | (mi.w ? 0x1000000u : 0u);
  lds_mask32[tid] = mw;
  if (tid < 32) { lds_tv[tid] = 0; lds_m[tid] = -1e30f; lds_l[tid] = 0.0f; }
  __syncthreads();
  if (mw) lds_tv[tid >> 4] = 1;

  bf16x8 qf[8];
  {
    const float* qrow = Q + ((size_t)b * TB + q0 + lo5) * DD + w * 128 + hi * 8;
    #pragma unroll
    for (int kk = 0; kk < 8; ++kk) {
      const float4 a = *(const float4*)(qrow + kk * 16);
      const float4 c = *(const float4*)(qrow + kk * 16 + 4);
      const float f[8] = {a.x * 0.03125f, a.y * 0.03125f, a.z * 0.03125f, a.w * 0.03125f,
                          c.x * 0.03125f, c.y * 0.03125f, c.z * 0.03125f, c.w * 0.03125f};
      qf[kk] = pack8(f);
    }
  }

  f32x16 oacc[4] = {f32x16{}, f32x16{}, f32x16{}, f32x16{}};
  const float* kbat = K + (size_t)b * TB * DD + w * 128 + hi * 8;
  const float* vbat = V + (size_t)b * TB * DD + w * 128;
  __syncthreads();

  const int nkt = (qt >> 1) + 1;
  for (int kt = 0; kt < nkt; ++kt) {
    if (!lds_tv[kt]) continue;
    const int k0 = kt << 6;
    f32x16 s0{}, s1{};
    const float* kb0 = kbat + (size_t)(k0 + lo5) * DD;
    #pragma unroll
    for (int kk = 0; kk < 8; ++kk) {
      const float4 a0 = *(const float4*)(kb0 + kk * 16);
      const float4 a1 = *(const float4*)(kb0 + kk * 16 + 4);
      const float f0[8] = {a0.x, a0.y, a0.z, a0.w, a1.x, a1.y, a1.z, a1.w};
      s0 = __builtin_amdgcn_mfma_f32_32x32x16_bf16(qf[kk], pack8(f0), s0, 0, 0, 0);
      const float4 b0 = *(const float4*)(kb0 + (size_t)32 * DD + kk * 16);
      const float4 b1 = *(const float4*)(kb0 + (size_t)32 * DD + kk * 16 + 4);
      const float f1[8] = {b0.x, b0.y, b0.z, b0.w, b1.x, b1.y, b1.z, b1.w};
      s1 = __builtin_amdgcn_mfma_f32_32x32x16_bf16(qf[kk], pack8(f1), s1, 0, 0, 0);
    }
    {
      float* wp = lds_part[w];
      const int pos = lo5 + (hi << 5);
      #pragma unroll
      for (int r = 0; r < 16; ++r) {
        wp[r * 68 + pos]        = s0[r];
        wp[(16 + r) * 68 + pos] = s1[r];
      }
    }
    __syncthreads();
    {
      const int r = tid >> 4, g = tid & 15;
      const int regp  = (r & 3) | (((r >> 3) & 3) << 2);
      const int plane = ((g >> 3) << 4) + regp;
      const int pos   = ((4 * g) & 31) + (((r >> 2) & 1) << 5);
      float s[4] = {0.f, 0.f, 0.f, 0.f};
      #pragma unroll
      for (int ww = 0; ww < 8; ++ww) {
        const float4 v4 = *(const float4*)&lds_part[ww][plane * 68 + pos];
        s[0] += v4.x; s[1] += v4.y; s[2] += v4.z; s[3] += v4.w;
      }
      const unsigned mv = lds_mask32[(k0 >> 2) + g];
      const int q = q0 + r;
      #pragma unroll
      for (int i = 0; i < 4; ++i) {
        const int kg = k0 + 4 * g + i;
        const bool ok = (((mv >> (8 * i)) & 0xffu) != 0u) && (kg <= q);
        if (!ok) s[i] = -1e30f;
      }
      float mx = fmaxf(fmaxf(s[0], s[1]), fmaxf(s[2], s[3]));
      #pragma unroll
      for (int d = 1; d < 16; d <<= 1) mx = fmaxf(mx, __shfl_xor(mx, d, 64));
      const float mold = lds_m[r];
      const float mnew = fmaxf(mold, mx);
      float p[4], ls = 0.f;
      #pragma unroll
      for (int i = 0; i < 4; ++i) { p[i] = __expf(s[i] - mnew); ls += p[i]; }
      #pragma unroll
      for (int d = 1; d < 16; d <<= 1) ls += __shfl_xor(ls, d, 64);
      const float resc = __expf(mold - mnew);
      if (g == 0) {
        lds_m[r]     = mnew;
        lds_l[r]     = lds_l[r] * resc + ls;
        lds_scale[r] = resc;
      }
      unsigned* pp = (unsigned*)&lds_P[r][4 * g];
      pp[0] = pack2(p[1], p[0]);
      pp[1] = pack2(p[3], p[2]);
    }
    __syncthreads();
    {
      float sc[16];
      #pragma unroll
      for (int reg = 0; reg < 16; ++reg)
        sc[reg] = lds_scale[(reg & 3) + ((reg >> 2) << 3) + (hi << 2)];
      #pragma unroll
      for (int nb = 0; nb < 4; ++nb)
        #pragma unroll
        for (int reg = 0; reg < 16; ++reg) oacc[nb][reg] *= sc[reg];
      bf16x8 pf[4];
      #pragma unroll
      for (int kc = 0; kc < 4; ++kc)
        pf[kc] = __builtin_bit_cast(bf16x8, *(const int4v*)&lds_P[lo5][kc * 16 + hi * 8]);
      const float* vb = vbat + (size_t)k0 * DD + lo5;
      #pragma unroll
      for (int kc = 0; kc < 4; ++kc) {
        const float* vr = vb + (size_t)(kc * 16 + hi * 8) * DD;
        float fv[4][8];
        #pragma unroll
        for (int j = 0; j < 8; ++j) {
          const float* vrj = vr + (size_t)j * DD;
          #pragma unroll
          for (int nb = 0; nb < 4; ++nb) fv[nb][j] = vrj[nb * 32];
        }
        #pragma unroll
        for (int nb = 0; nb < 4; ++nb)
          oacc[nb] = __builtin_amdgcn_mfma_f32_32x32x16_bf16(pf[kc], pack8(fv[nb]), oacc[nb], 0, 0, 0);
      }
    }
  }

  float il[16];
  #pragma unroll
  for (int reg = 0; reg < 16; ++reg)
    il[reg] = 1.0f / lds_l[(reg & 3) + ((reg >> 2) << 3) + (hi << 2)];
  float* ob = O + ((size_t)b * TB + q0) * DD + w * 128;
  #pragma unroll
  for (int nb = 0; nb < 4; ++nb) {
    #pragma unroll
    for (int reg = 0; reg < 16; ++reg) {
      const int row = (reg & 3) + ((reg >> 2) << 3) + (hi << 2);
      ob[(size_t)row * DD + nb * 32 + lo5] = oacc[nb][reg] * il[reg];
    }
  }
}

extern "C" void kernel_launch(void* const* d_in, const int* in_sizes, int n_in,
                              void* d_out, int out_size, void* d_ws, size_t ws_size,
                              hipStream_t stream) {
  const float* Q  = (const float*)d_in[0];
  const float* K  = (const float*)d_in[1];
  const float* V  = (const float*)d_in[2];
  const int*   AM = (const int*)d_in[3];
  float* O = (float*)d_out;
  (void)in_sizes; (void)n_in; (void)out_size;

  const size_t kf_bytes = (size_t)4 * 64 * 64 * 64 * 8 * 2;   // 16.78 MB
  const size_t vf_bytes = (size_t)4 * 32 * 128 * 64 * 8 * 2;  // 16.78 MB
  if (ws_size >= kf_bytes + vf_bytes) {
    unsigned short* Kf = (unsigned short*)d_ws;
    unsigned short* Vf = (unsigned short*)((char*)d_ws + kf_bytes);
    hipLaunchKernelGGL(conv_k_bf16, dim3(256), dim3(256), 0, stream, K, Kf);
    hipLaunchKernelGGL(conv_v_bf16t, dim3(512), dim3(256), 0, stream, V, Vf);
    hipLaunchKernelGGL(fa_fwd_f32_v2, dim3(256), dim3(512), 0, stream, Q, AM, Kf, Vf, O);
  } else {
    hipLaunchKernelGGL(fa_fwd_f32_v1, dim3(256), dim3(512), 0, stream, Q, K, V, AM, O);
  }
}